// Round 3
// baseline (231.610 us; speedup 1.0000x reference)
//
#include <hip/hip_runtime.h>
#include <hip/hip_bf16.h>

// MANN: gating MLP (32->128->128->8) + 3 phase-blended expert layers.
// B=512, IN_DIM=480, OUT_DIM=400, HID=512, K=8 experts.
// Inputs fp32 (device-verified via detect kernel; bf16 fallback kept for
// robustness). OUTPUT fp32. Per layer: K=8 expert GEMMs (split-K over
// grid.z) with mfma_f32_16x16x32_bf16 (fp32 inputs RNE-converted to bf16
// in-register; fp32 accumulate), g-scaled fp32 partials in ws; blend kernel
// sums partials + blended bias + elu. Intermediates A1/A2 bf16.

typedef __hip_bfloat16 bf16;
typedef __attribute__((ext_vector_type(8))) short bf16x8;
typedef __attribute__((ext_vector_type(4))) float f32x4;

__device__ __forceinline__ float elu1(float x) { return x > 0.f ? x : expm1f(x); }

__device__ __forceinline__ float ldf(const void* base, size_t i, int f32) {
    return f32 ? ((const float*)base)[i]
               : __bfloat162float(((const bf16*)base)[i]);
}

__device__ __forceinline__ short cvt1(float v) {
    union { bf16 h; unsigned short u; } c;
    c.h = __float2bfloat16(v);          // RNE
    return (short)c.u;
}

__device__ __forceinline__ bf16x8 frag_load(const void* base, size_t elt, int f32) {
    if (f32) {
        const float* p = (const float*)base + elt;
        float4 a = *(const float4*)p;
        float4 b = *(const float4*)(p + 4);
        bf16x8 r;
        r[0] = cvt1(a.x); r[1] = cvt1(a.y); r[2] = cvt1(a.z); r[3] = cvt1(a.w);
        r[4] = cvt1(b.x); r[5] = cvt1(b.y); r[6] = cvt1(b.z); r[7] = cvt1(b.w);
        return r;
    }
    return *(const bf16x8*)((const bf16*)base + elt);
}

// ---------------- dtype detection ----------------
// GW1 (4096 weights, sigma~0.18) viewed as 16-bit halves: if bf16, the
// exponent field never reaches 129 (|v|>=4); if fp32, the low halves are
// random mantissa bits -> ~50% have exp-field >= 129.
__global__ __launch_bounds__(256) void detect_kernel(const unsigned short* w, int* flag) {
    __shared__ int sh[256];
    int cnt = 0;
    for (int i = threadIdx.x; i < 2048; i += 256) {
        int e = (w[i] >> 7) & 0xFF;
        if (e >= 129) cnt++;
    }
    sh[threadIdx.x] = cnt;
    __syncthreads();
    for (int s = 128; s > 0; s >>= 1) {
        if ((int)threadIdx.x < s) sh[threadIdx.x] += sh[threadIdx.x + s];
        __syncthreads();
    }
    if (threadIdx.x == 0) *flag = (sh[0] > 64) ? 1 : 0;
}

// ---------------- gating MLP ----------------
__global__ __launch_bounds__(128) void gating_kernel(
    const void* __restrict__ x, const int* __restrict__ idx_raw,
    const void* __restrict__ GW1, const void* __restrict__ Gb1,
    const void* __restrict__ GW2, const void* __restrict__ Gb2,
    const void* __restrict__ GW3, const void* __restrict__ Gb3,
    const int* __restrict__ flag, float* __restrict__ g)
{
    __shared__ float xg[32];
    __shared__ float h1[128];
    __shared__ float h2[128];
    const int f = *flag;
    const int b = blockIdx.x;
    const int j = threadIdx.x;

    if (j < 32) {
        // gating_idx may arrive as int32 or int64; word1==0 iff int64
        int ii;
        if (idx_raw[1] == 0) ii = (int)((const long long*)idx_raw)[j];
        else                 ii = idx_raw[j];
        if (ii < 0 || ii >= 480) ii = 448 + j;  // memory-safety clamp
        xg[j] = ldf(x, (size_t)b * 480 + ii, f);
    }
    __syncthreads();

    float a = ldf(Gb1, j, f);
    #pragma unroll
    for (int i = 0; i < 32; ++i) a += xg[i] * ldf(GW1, i * 128 + j, f);
    h1[j] = elu1(a);
    __syncthreads();

    float a2 = ldf(Gb2, j, f);
    #pragma unroll 8
    for (int i = 0; i < 128; ++i) a2 += h1[i] * ldf(GW2, i * 128 + j, f);
    h2[j] = elu1(a2);
    __syncthreads();

    if (j < 8) {
        float a3 = ldf(Gb3, j, f);
        for (int i = 0; i < 128; ++i) a3 += h2[i] * ldf(GW3, i * 8 + j, f);
        g[b * 8 + j] = a3;  // no activation on blend coefficients
    }
}

// ---------------- one expert's partial GEMM (split-K over grid.z) ----------
// part[k][b][o] = g[b,k] * sum_i A[b,i] * W[k,o,i]
// grid: (ceil(ODIM/64), 512/64, 8), block 256 (4 waves, each a 16x64 strip)
// a_mode: 0 -> A is always bf16 (ws intermediate); 1 -> A follows *flag.
template <int IDIM, int ODIM>
__global__ __launch_bounds__(256) void expert_gemm(
    const void* __restrict__ A,    // [512, IDIM]
    const void* __restrict__ W,    // [8, ODIM, IDIM]
    const float* __restrict__ g,   // [512, 8]
    const int* __restrict__ flag, int a_mode,
    float* __restrict__ part)      // [8, 512, 512]
{
    const int f    = *flag;
    const int af   = a_mode ? f : 0;
    const int k    = blockIdx.z;
    const int rowb = blockIdx.y * 64;
    const int ob   = blockIdx.x * 64;
    const int wave = threadIdx.x >> 6;
    const int lane = threadIdx.x & 63;
    const int m    = lane & 15;   // A row within 16 / C col within 16
    const int quad = lane >> 4;   // 0..3

    // A fragment: row (rowb+16*wave+m), k-range quad*8..+7
    size_t a_off = (size_t)(rowb + 16 * wave + m) * IDIM + quad * 8;

    // B fragments (4 col tiles): W row o = ob+16*t+m, k-range quad*8..+7
    size_t b_off[4];
    #pragma unroll
    for (int t = 0; t < 4; ++t) {
        int o = ob + 16 * t + m;
        if (o >= ODIM) o = ODIM - 1;  // clamp (stores of garbage cols never read)
        b_off[t] = ((size_t)k * ODIM + o) * IDIM + quad * 8;
    }

    const f32x4 zero = {0.f, 0.f, 0.f, 0.f};
    f32x4 acc[4] = {zero, zero, zero, zero};

    for (int i0 = 0; i0 < IDIM; i0 += 32) {
        bf16x8 afr = frag_load(A, a_off, af);
        a_off += 32;
        #pragma unroll
        for (int t = 0; t < 4; ++t) {
            bf16x8 bfr = frag_load(W, b_off[t], f);
            b_off[t] += 32;
            acc[t] = __builtin_amdgcn_mfma_f32_16x16x32_bf16(afr, bfr, acc[t], 0, 0, 0);
        }
    }

    // C/D layout: row (batch, from A) = 4*quad + reg, col (o, from B) = lane&15
    const int orow0 = rowb + 16 * wave + 4 * quad;
    float gv[4];
    #pragma unroll
    for (int r = 0; r < 4; ++r) gv[r] = g[(orow0 + r) * 8 + k];

    #pragma unroll
    for (int t = 0; t < 4; ++t) {
        #pragma unroll
        for (int r = 0; r < 4; ++r) {
            part[((size_t)k * 512 + (orow0 + r)) * 512 + (ob + 16 * t + m)] =
                acc[t][r] * gv[r];
        }
    }
}

// ---------------- blend partials + bias, activation ------------------------
// OutT: bf16 for intermediates (feed next MFMA), float for final output.
template <bool ELU, typename OutT>
__global__ __launch_bounds__(256) void blend_kernel(
    const float* __restrict__ part,  // [8, 512, 512]
    const float* __restrict__ g,     // [512, 8]
    const void* __restrict__ bk,     // [8, ODIM]
    const int* __restrict__ flag,
    OutT* __restrict__ out,          // [512, ODIM]
    int ODIM)
{
    const int f = *flag;
    const int b = blockIdx.x;
    float gv[8];
    #pragma unroll
    for (int k = 0; k < 8; ++k) gv[k] = g[b * 8 + k];

    for (int o = threadIdx.x; o < ODIM; o += 256) {
        float s = 0.f;
        #pragma unroll
        for (int k = 0; k < 8; ++k)
            s += part[((size_t)k * 512 + b) * 512 + o] +
                 gv[k] * ldf(bk, k * ODIM + o, f);
        if (ELU) s = elu1(s);
        out[(size_t)b * ODIM + o] = (OutT)s;
    }
}

extern "C" void kernel_launch(void* const* d_in, const int* in_sizes, int n_in,
                              void* d_out, int out_size, void* d_ws, size_t ws_size,
                              hipStream_t stream)
{
    const void* x   = d_in[0];
    const int* gidx = (const int*)d_in[1];
    const void* GW1 = d_in[2];
    const void* Gb1 = d_in[3];
    const void* GW2 = d_in[4];
    const void* Gb2 = d_in[5];
    const void* GW3 = d_in[6];
    const void* Gb3 = d_in[7];
    const void* Wk1 = d_in[8];
    const void* bk1 = d_in[9];
    const void* Wk2 = d_in[10];
    const void* bk2 = d_in[11];
    const void* Wk3 = d_in[12];
    const void* bk3 = d_in[13];

    char* ws = (char*)d_ws;
    float* g    = (float*)ws;                                   // 16 KB
    float* part = (float*)(ws + (16 << 10));                    // 8 MB
    bf16*  A1   = (bf16*)(ws + (16 << 10) + (8 << 20));         // 512 KB
    bf16*  A2   = (bf16*)(ws + (16 << 10) + (8 << 20) + (512 << 10));
    int*   flag = (int*)(ws + (16 << 10) + (8 << 20) + (1 << 20));

    detect_kernel<<<1, 256, 0, stream>>>((const unsigned short*)GW1, flag);

    gating_kernel<<<512, 128, 0, stream>>>(x, gidx, GW1, Gb1, GW2, Gb2, GW3, Gb3,
                                           flag, g);

    // Layer 1: [512,480] x [8,512,480] -> A1 [512,512] (bf16)
    expert_gemm<480, 512><<<dim3(8, 8, 8), 256, 0, stream>>>(x, Wk1, g, flag, 1, part);
    blend_kernel<true, bf16><<<512, 256, 0, stream>>>(part, g, bk1, flag, A1, 512);

    // Layer 2: [512,512] x [8,512,512] -> A2 [512,512] (bf16)
    expert_gemm<512, 512><<<dim3(8, 8, 8), 256, 0, stream>>>(A1, Wk2, g, flag, 0, part);
    blend_kernel<true, bf16><<<512, 256, 0, stream>>>(part, g, bk2, flag, A2, 512);

    // Layer 3: [512,512] x [8,400,512] -> out [512,400] (fp32)
    expert_gemm<512, 400><<<dim3(7, 8, 8), 256, 0, stream>>>(A2, Wk3, g, flag, 0, part);
    blend_kernel<false, float><<<512, 256, 0, stream>>>(part, g, bk3, flag,
                                                        (float*)d_out, 400);
}

// Round 4
// 140.498 us; speedup vs baseline: 1.6485x; 1.6485x over previous
//
#include <hip/hip_runtime.h>
#include <hip/hip_bf16.h>

// MANN fused: gating MLP + 3 phase-blended expert layers, 4 launches total.
// B=512, IN_DIM=480, OUT_DIM=400, HID=512, K=8 experts. Inputs fp32, out fp32.
// Layer kernel: block = (o-tile 16 cols, m-tile 64 rows); all 8 experts' W
// slice staged fp32->bf16 into LDS in K-windows of 128 (double-buffered
// 2x32KB, XOR-swizzled chunks for bank-conflict-free ds_read_b128); waves own
// 2 experts x 64 rows; A-frags straight from global bf16 (L1-shared across
// waves); epilogue blends experts (g-scale + g*bias) via LDS reuse -> no
// global partials, no blend kernels. Grid decode o=idx%32 colocates the 8
// same-o blocks on one XCD so W is HBM-fetched once, L2 serves the reuse.

typedef __hip_bfloat16 bf16;
typedef unsigned short u16;
typedef __attribute__((ext_vector_type(8))) short bf16x8;
typedef __attribute__((ext_vector_type(4))) float f32x4;

__device__ __forceinline__ float elu1(float x) { return x > 0.f ? x : expm1f(x); }

__device__ __forceinline__ short cvt1(float v) {
    union { bf16 h; u16 u; } c;
    c.h = __float2bfloat16(v);          // RNE
    return (short)c.u;
}

// ---------------- gating MLP + x -> bf16 conversion ----------------
__global__ __launch_bounds__(128) void gating_xcvt_kernel(
    const float* __restrict__ x, const int* __restrict__ idx_raw,
    const float* __restrict__ GW1, const float* __restrict__ Gb1,
    const float* __restrict__ GW2, const float* __restrict__ Gb2,
    const float* __restrict__ GW3, const float* __restrict__ Gb3,
    float* __restrict__ g, u16* __restrict__ xbf)
{
    __shared__ float xg[32];
    __shared__ float h1[128];
    __shared__ float h2[128];
    const int b = blockIdx.x;
    const int j = threadIdx.x;

    // convert this row of x to bf16 for the layer-1 A operand
    for (int i = j; i < 480; i += 128)
        xbf[b * 480 + i] = (u16)cvt1(x[b * 480 + i]);

    if (j < 32) {
        // gating_idx may arrive as int32 or int64; word1==0 iff int64
        int ii;
        if (idx_raw[1] == 0) ii = (int)((const long long*)idx_raw)[j];
        else                 ii = idx_raw[j];
        if (ii < 0 || ii >= 480) ii = 448 + j;  // memory-safety clamp
        xg[j] = x[(size_t)b * 480 + ii];
    }
    __syncthreads();

    float a = Gb1[j];
    #pragma unroll
    for (int i = 0; i < 32; ++i) a += xg[i] * GW1[i * 128 + j];
    h1[j] = elu1(a);
    __syncthreads();

    float a2 = Gb2[j];
    #pragma unroll 8
    for (int i = 0; i < 128; ++i) a2 += h1[i] * GW2[i * 128 + j];
    h2[j] = elu1(a2);
    __syncthreads();

    if (j < 8) {
        float a3 = Gb3[j];
        for (int i = 0; i < 128; ++i) a3 += h2[i] * GW3[i * 8 + j];
        g[b * 8 + j] = a3;  // no activation on blend coefficients
    }
}

// ---------------- fused blended layer ----------------
// out[b,o] = act( sum_k g[b,k] * ( sum_i A[b,i]*Wk[k,o,i] + bk[k,o] ) )
// grid 256 (1D): o_tile = idx & 31 (16 cols), m_tile = idx >> 5 (64 rows).
template <int IDIM, int ODIM, bool ELU, typename OutT>
__global__ __launch_bounds__(256) void layer_kernel(
    const u16*  __restrict__ A,    // [512, IDIM] bf16
    const float* __restrict__ W,   // [8, ODIM, IDIM] fp32
    const float* __restrict__ bk,  // [8, ODIM] fp32
    const float* __restrict__ g,   // [512, 8] fp32
    OutT* __restrict__ out)        // [512, ODIM]
{
    constexpr int KW = 128;                       // K-window
    constexpr int NW = (IDIM + KW - 1) / KW;      // 4 for IDIM=480 and 512
    __shared__ u16 wbuf[2][8 * 16 * KW];          // 2 x 32 KB

    const int ot = blockIdx.x & 31;
    const int o0 = ot * 16;
    if (o0 >= ODIM) return;                       // whole block (L3: ot>=25)
    const int m0  = (blockIdx.x >> 5) * 64;
    const int tid  = threadIdx.x;
    const int wid  = tid >> 6;
    const int lane = tid & 63;
    const int n    = lane & 15;    // B out-col within tile / A row within 16
    const int quad = lane >> 4;
    const int e0   = wid * 2;      // this wave's expert pair

    // ---- staging helpers: 2048 units of 8 elems; unit u -> row r=u>>4
    // (r = e*16+nr), chunk c=u&15; LDS slot chunk = c ^ (nr&7) (swizzle). ----
    float4 lv[16];
    auto load_units = [&](int w) {
        const int w0 = w * KW;
        #pragma unroll
        for (int jj = 0; jj < 8; ++jj) {
            const int u = tid + 256 * jj;
            const int r = u >> 4, c = u & 15;
            const int e = r >> 4, nr = r & 15;
            if (w0 + c * 8 + 8 <= IDIM) {
                const float* p = W + ((size_t)(e * ODIM + o0 + nr)) * IDIM + w0 + c * 8;
                lv[2 * jj]     = *(const float4*)p;
                lv[2 * jj + 1] = *(const float4*)(p + 4);
            } else {
                lv[2 * jj]     = float4{0.f, 0.f, 0.f, 0.f};
                lv[2 * jj + 1] = float4{0.f, 0.f, 0.f, 0.f};
            }
        }
    };
    auto write_units = [&](u16* buf) {
        #pragma unroll
        for (int jj = 0; jj < 8; ++jj) {
            const int u = tid + 256 * jj;
            const int r = u >> 4, c = u & 15;
            const int nr = r & 15;
            bf16x8 hv;
            hv[0] = cvt1(lv[2 * jj].x);     hv[1] = cvt1(lv[2 * jj].y);
            hv[2] = cvt1(lv[2 * jj].z);     hv[3] = cvt1(lv[2 * jj].w);
            hv[4] = cvt1(lv[2 * jj + 1].x); hv[5] = cvt1(lv[2 * jj + 1].y);
            hv[6] = cvt1(lv[2 * jj + 1].z); hv[7] = cvt1(lv[2 * jj + 1].w);
            *(bf16x8*)(buf + r * KW + ((c ^ (nr & 7)) << 3)) = hv;
        }
    };

    const f32x4 zero = {0.f, 0.f, 0.f, 0.f};
    f32x4 acc[4][2] = {{zero, zero}, {zero, zero}, {zero, zero}, {zero, zero}};

    load_units(0);
    write_units(wbuf[0]);
    __syncthreads();

    for (int w = 0; w < NW; ++w) {
        if (w + 1 < NW) load_units(w + 1);   // prefetch next window (regs)

        const u16* buf = wbuf[w & 1];
        #pragma unroll
        for (int cl = 0; cl < KW / 32; ++cl) {
            const int i0 = w * KW + cl * 32;
            if (i0 >= IDIM) break;           // trims last window (IDIM=480)
            bf16x8 af[4];
            #pragma unroll
            for (int s = 0; s < 4; ++s)
                af[s] = *(const bf16x8*)(A + (size_t)(m0 + 16 * s + n) * IDIM
                                           + i0 + quad * 8);
            const int cw = cl * 4 + quad;
            #pragma unroll
            for (int e = 0; e < 2; ++e) {
                bf16x8 bfr = *(const bf16x8*)(buf + ((e0 + e) * 16 + n) * KW
                                                  + ((cw ^ (n & 7)) << 3));
                #pragma unroll
                for (int s = 0; s < 4; ++s)
                    acc[s][e] = __builtin_amdgcn_mfma_f32_16x16x32_bf16(
                                    af[s], bfr, acc[s][e], 0, 0, 0);
            }
        }

        if (w + 1 < NW) write_units(wbuf[(w + 1) & 1]);
        __syncthreads();
    }

    // ---- epilogue: per-wave expert-pair blend, cross-wave sum via LDS ----
    // C/D layout: col = lane&15 (=n, out col), row = quad*4 + reg (batch).
    const float bk0 = bk[e0 * ODIM + o0 + n];
    const float bk1 = bk[(e0 + 1) * ODIM + o0 + n];
    float* part = (float*)wbuf;              // [4][16][68] fp32, 17.4 KB
    #pragma unroll
    for (int s = 0; s < 4; ++s) {
        f32x4 v;
        #pragma unroll
        for (int r = 0; r < 4; ++r) {
            const int row = m0 + 16 * s + quad * 4 + r;
            const float gA = g[row * 8 + e0];
            const float gB = g[row * 8 + e0 + 1];
            v[r] = gA * (acc[s][0][r] + bk0) + gB * (acc[s][1][r] + bk1);
        }
        *(f32x4*)(part + (wid * 16 + n) * 68 + 16 * s + quad * 4) = v;
    }
    __syncthreads();

    // wave wid reduces rows [16*wid, 16*wid+16)
    f32x4 t = zero;
    #pragma unroll
    for (int w4 = 0; w4 < 4; ++w4)
        t += *(const f32x4*)(part + (w4 * 16 + n) * 68 + 16 * wid + quad * 4);
    #pragma unroll
    for (int r = 0; r < 4; ++r) {
        float val = t[r];
        if (ELU) val = elu1(val);
        const int row = m0 + 16 * wid + quad * 4 + r;
        if constexpr (__hip_internal::is_same<OutT, float>::value)
            out[(size_t)row * ODIM + o0 + n] = val;
        else
            out[(size_t)row * ODIM + o0 + n] = (OutT)cvt1(val);
    }
}

extern "C" void kernel_launch(void* const* d_in, const int* in_sizes, int n_in,
                              void* d_out, int out_size, void* d_ws, size_t ws_size,
                              hipStream_t stream)
{
    const float* x   = (const float*)d_in[0];
    const int* gidx  = (const int*)d_in[1];
    const float* GW1 = (const float*)d_in[2];
    const float* Gb1 = (const float*)d_in[3];
    const float* GW2 = (const float*)d_in[4];
    const float* Gb2 = (const float*)d_in[5];
    const float* GW3 = (const float*)d_in[6];
    const float* Gb3 = (const float*)d_in[7];
    const float* Wk1 = (const float*)d_in[8];
    const float* bk1 = (const float*)d_in[9];
    const float* Wk2 = (const float*)d_in[10];
    const float* bk2 = (const float*)d_in[11];
    const float* Wk3 = (const float*)d_in[12];
    const float* bk3 = (const float*)d_in[13];

    char* ws  = (char*)d_ws;
    float* g  = (float*)ws;                    // 16 KB
    u16*  xbf = (u16*)(ws + (16 << 10));       // 480 KB
    u16*  A1  = (u16*)(ws + (1 << 20));        // 512 KB
    u16*  A2  = (u16*)(ws + (1 << 20) + (512 << 10));

    gating_xcvt_kernel<<<512, 128, 0, stream>>>(x, gidx, GW1, Gb1, GW2, Gb2,
                                                GW3, Gb3, g, xbf);

    layer_kernel<480, 512, true,  u16>  <<<256, 256, 0, stream>>>(xbf, Wk1, bk1, g, A1);
    layer_kernel<512, 512, true,  u16>  <<<256, 256, 0, stream>>>(A1,  Wk2, bk2, g, A2);
    layer_kernel<512, 400, false, float><<<256, 256, 0, stream>>>(A2,  Wk3, bk3, g,
                                                                  (float*)d_out);
}